// Round 7
// baseline (1752.755 us; speedup 1.0000x reference)
//
#include <hip/hip_runtime.h>

typedef _Float16 f16;
typedef _Float16 f16x8 __attribute__((ext_vector_type(8)));
typedef _Float16 f16x4 __attribute__((ext_vector_type(4)));
typedef float    f32x4 __attribute__((ext_vector_type(4)));
typedef unsigned long long ull;

static constexpr int Bb  = 32;
static constexpr int Tt  = 128;
static constexpr int HID = 1024;
static constexpr int ZD  = 256;
static constexpr int DE  = 512;
static constexpr int VOC = 32000;
static constexpr int BT  = Bb * Tt;   // 4096
static constexpr int G4  = 4 * HID;   // 4096
static constexpr int NB  = 64;        // lstm blocks (16 hidden units each)

// ---- async global->LDS, 16B per lane; LDS dest = wave-uniform base + lane*16 ----
__device__ __forceinline__ void gld_lds16(const void* g, void* l) {
  __builtin_amdgcn_global_load_lds((const __attribute__((address_space(1))) unsigned int*)g,
                                   (__attribute__((address_space(3))) unsigned int*)l,
                                   16, 0, 0);
}

// ---------------- f32 -> f16 convert (vectorized) ----------------
__global__ void cvt_kernel(const float* __restrict__ s, f16* __restrict__ d, int n4) {
  int i = blockIdx.x * blockDim.x + threadIdx.x;
  int st = gridDim.x * blockDim.x;
  for (; i < n4; i += st) {
    float4 v = ((const float4*)s)[i];
    f16x4 o = { (f16)v.x, (f16)v.y, (f16)v.z, (f16)v.w };
    ((f16x4*)d)[i] = o;
  }
}

// ---------------- embedding gather -> f16 ----------------
__global__ void gather_kernel(const float* __restrict__ emb, const int* __restrict__ x,
                              f16* __restrict__ E) {
  int g = blockIdx.x * 256 + threadIdx.x;   // BT*DE/8 threads
  int m = g >> 6, seg = (g & 63) * 8;
  int idx = x[m];
  const float* src = emb + (size_t)idx * DE + seg;
  float4 a = *(const float4*)src;
  float4 b = *(const float4*)(src + 4);
  f16x8 o = { (f16)a.x,(f16)a.y,(f16)a.z,(f16)a.w,(f16)b.x,(f16)b.y,(f16)b.z,(f16)b.w };
  *(f16x8*)(E + (size_t)m * DE + seg) = o;
}

// ---------------- bias sum ----------------
__global__ void bsum_kernel(const float* __restrict__ a, const float* __restrict__ b,
                            float* __restrict__ o, int n) {
  int i = blockIdx.x * blockDim.x + threadIdx.x;
  if (i < n) o[i] = a[i] + b[i];
}

// ---------------- h0 = tanh(z @ W_h^T + b_h), store f16 ----------------
__global__ __launch_bounds__(256) void h0_kernel(const float* __restrict__ z,
                                                 const float* __restrict__ W_h,
                                                 const float* __restrict__ b_h,
                                                 f16* __restrict__ h0f) {
  __shared__ float zs[32][260];
  __shared__ float wsl[8][260];
  const int jc = blockIdx.x, tid = threadIdx.x;
  #pragma unroll
  for (int it = 0; it < 8; ++it) {
    int idx = it * 256 + tid;
    float4 v = ((const float4*)z)[idx];
    int b = idx >> 6, k = (idx & 63) * 4;
    zs[b][k] = v.x; zs[b][k+1] = v.y; zs[b][k+2] = v.z; zs[b][k+3] = v.w;
  }
  #pragma unroll
  for (int it = 0; it < 2; ++it) {
    int idx = it * 256 + tid;
    float4 v = ((const float4*)(W_h + (size_t)jc * 8 * ZD))[idx];
    int r = idx >> 6, k = (idx & 63) * 4;
    wsl[r][k] = v.x; wsl[r][k+1] = v.y; wsl[r][k+2] = v.z; wsl[r][k+3] = v.w;
  }
  __syncthreads();
  const int b = tid >> 3, jj = tid & 7;
  const int j = jc * 8 + jj;
  float acc = b_h[j];
  for (int k = 0; k < ZD; ++k) acc += zs[b][k] * wsl[jj][k];
  h0f[(size_t)b * HID + j] = (f16)tanhf(acc);
}

// ---------------- GEMM: C = A[M,K] @ B[N,K]^T + bias[N]  (f16 in, f32 out) --------
// XGOUT: C laid out [g][b][t] float (for the x-gate GEMM).
// AHS2 : A is the LSTM h-state in chunk layout [t][blk][b][u] (halves), i.e.
//        A[m][k] at half-index ((m&127)*64 + (k>>4))*512 + (m>>7)*16 + (k&15).
template <bool XGOUT, bool AHS2>
__global__ __launch_bounds__(256, 2) void gemm_kernel(
    const f16* __restrict__ A, const f16* __restrict__ B,
    const float* __restrict__ bias, float* __restrict__ C,
    int M, int N, int K) {
  __shared__ f16 As[128 * 64];
  __shared__ f16 Bs[128 * 64];
  const int n0 = blockIdx.x * 128, m0 = blockIdx.y * 128;
  const int tid = threadIdx.x, wid = tid >> 6, lane = tid & 63;
  const int wm = wid >> 1, wn = wid & 1;
  const int sr = lane >> 3, sk = (lane & 7) * 8;
  f32x4 acc[4][4] = {};
  for (int k0 = 0; k0 < K; k0 += 64) {
    __syncthreads();
    #pragma unroll
    for (int i = 0; i < 4; ++i) {
      int rr = (wid * 4 + i) * 8;
      const f16* asrc;
      if (AHS2) {
        int m = m0 + rr + sr, k = k0 + sk;
        asrc = A + ((size_t)(m & 127) * 64 + (k >> 4)) * 512 + (m >> 7) * 16 + (k & 15);
      } else {
        asrc = A + (size_t)(m0 + rr + sr) * K + k0 + sk;
      }
      gld_lds16(asrc, &As[rr * 64]);
      gld_lds16(B + (size_t)(n0 + rr + sr) * K + k0 + sk, &Bs[rr * 64]);
    }
    __syncthreads();
    #pragma unroll
    for (int ks = 0; ks < 2; ++ks) {
      f16x8 af[4], bf[4];
      #pragma unroll
      for (int mt = 0; mt < 4; ++mt)
        af[mt] = *(const f16x8*)&As[(wm * 64 + mt * 16 + (lane & 15)) * 64 + ks * 32 + (lane >> 4) * 8];
      #pragma unroll
      for (int nt = 0; nt < 4; ++nt)
        bf[nt] = *(const f16x8*)&Bs[(wn * 64 + nt * 16 + (lane & 15)) * 64 + ks * 32 + (lane >> 4) * 8];
      #pragma unroll
      for (int mt = 0; mt < 4; ++mt)
        #pragma unroll
        for (int nt = 0; nt < 4; ++nt)
          acc[mt][nt] = __builtin_amdgcn_mfma_f32_16x16x32_f16(af[mt], bf[nt], acc[mt][nt], 0, 0, 0);
    }
  }
  #pragma unroll
  for (int nt = 0; nt < 4; ++nt) {
    int col = n0 + wn * 64 + nt * 16 + (lane & 15);
    float bv = bias[col];
    #pragma unroll
    for (int mt = 0; mt < 4; ++mt) {
      int row = m0 + wm * 64 + mt * 16 + (lane >> 4) * 4;
      if (XGOUT) {
        int b = row >> 7, t0 = row & 127;
        float4 v = { acc[mt][nt][0] + bv, acc[mt][nt][1] + bv,
                     acc[mt][nt][2] + bv, acc[mt][nt][3] + bv };
        *(float4*)&C[((size_t)col * 32 + b) * 128 + t0] = v;
      } else {
        #pragma unroll
        for (int p = 0; p < 4; ++p)
          C[(size_t)(row + p) * N + col] = acc[mt][nt][p] + bv;
      }
    }
  }
}

// ---------------- persistent LSTM recurrence (v6: packed-chunk exchange) ---------
// 64 blocks x 512 threads (8 waves). Block bid owns 16 hidden units (64 gate rows),
// W_hh fragments in VGPRs (wave wid owns k-range wid*128..+128).
// Exchange: h_t slice -> LDS tile -> wave 0 stores ONE contiguous 1KB chunk
// (agent-scope, bypasses non-coherent XCD L2) -> vmcnt(0) on just those -> flag.
// Consumers: wave w polls flags 8w..8w+8 and stages those chunks as they land
// (per-producer pipelining). No fences/wbl2/buffer_inv; XG2/Whh stay L2-resident.
__global__ __launch_bounds__(512, 1) void lstm_kernel(
    const f16* __restrict__ Whh16,   // [4096][1024]
    const float* __restrict__ XG2,   // [g][b][t] : ((g*32)+b)*128+t
    const f16* __restrict__ h0f,     // [32][1024]
    f16* __restrict__ HS2,           // [t][blk][b][u] chunks: ((t*64+blk)*32+b)*16+u
    unsigned int* __restrict__ bar) {// bar[0..63]: per-block completed-step flags
  const int bid = blockIdx.x, tid = threadIdx.x;
  const int lane = tid & 63, wid = tid >> 6;
  const int lr = lane & 15, hi = lane >> 4;
  const int j0 = bid * 16;
  __shared__ __align__(16) f16 hl[32][1032];       // h_{t-1}, batch-major, +8 pad
  __shared__ float part[8][64][33];                // per-wave K-partials
  __shared__ __align__(16) f16 hs_out[32][16];     // this block's h_t tile [b][u]

  // preload W fragments (once): wave wid covers k in [wid*128, wid*128+128)
  f16x8 wfrag[4][4];
  #pragma unroll
  for (int rt = 0; rt < 4; ++rt) {                 // rt = gate q; row u = lr
    int g = rt * HID + j0 + lr;
    #pragma unroll
    for (int kk = 0; kk < 4; ++kk)
      wfrag[rt][kk] = *(const f16x8*)(Whh16 + (size_t)g * HID + wid * 128 + kk * 32 + hi * 8);
  }

  const int ub = tid & 15, bb = tid >> 4;          // thread owns (unit ub, batch bb)
  float creg = 0.f;

  for (int t = 0; t < Tt; ++t) {
    // ---- XG prefetch (plain cached loads; 128B line serves 32 steps from L2) ----
    float xg[4];
    #pragma unroll
    for (int q = 0; q < 4; ++q)
      xg[q] = XG2[((size_t)(q * HID + j0 + ub) * 32 + bb) * 128 + t];

    if (t == 0) {
      // stage h0: wave wid loads batch rows 4*wid..+4 (plain loads, kernel-boundary coherent)
      #pragma unroll
      for (int r = 0; r < 4; ++r) {
        int row = wid * 4 + r;
        const ull* hb = (const ull*)(h0f + (size_t)row * HID);
        #pragma unroll
        for (int c = 0; c < 4; ++c) {
          ull v = hb[c * 64 + lane];
          *(ull*)&hl[row][(c * 64 + lane) * 4] = v;
        }
      }
    } else {
      // wave wid: poll flags 8*wid..+8, then stage those 8 chunks (1KB each)
      const unsigned tgt = (unsigned)t;
      for (;;) {
        unsigned f = __hip_atomic_load(&bar[wid * 8 + (lane & 7)],
                                       __ATOMIC_RELAXED, __HIP_MEMORY_SCOPE_AGENT);
        if (__all(f >= tgt)) break;
      }
      const int b = lane >> 1, u0 = (lane & 1) * 8;
      #pragma unroll
      for (int c = 0; c < 8; ++c) {
        int blk = wid * 8 + c;
        const ull* src = (const ull*)(HS2 + ((size_t)(t - 1) * 64 + blk) * 512);
        ull a0 = __hip_atomic_load(src + lane * 2,     __ATOMIC_RELAXED, __HIP_MEMORY_SCOPE_AGENT);
        ull a1 = __hip_atomic_load(src + lane * 2 + 1, __ATOMIC_RELAXED, __HIP_MEMORY_SCOPE_AGENT);
        *(ull*)&hl[b][blk * 16 + u0]     = a0;
        *(ull*)&hl[b][blk * 16 + u0 + 4] = a1;
      }
    }
    __syncthreads();

    // ---- gate MFMA: C[64 gate rows][32 batches], this wave's k-eighth ----
    {
      f32x4 acc[4][2] = {};
      #pragma unroll
      for (int kk = 0; kk < 4; ++kk) {
        int ko = wid * 128 + kk * 32 + hi * 8;
        f16x8 bf0 = *(const f16x8*)&hl[lr][ko];
        f16x8 bf1 = *(const f16x8*)&hl[16 + lr][ko];
        #pragma unroll
        for (int rt = 0; rt < 4; ++rt) {
          acc[rt][0] = __builtin_amdgcn_mfma_f32_16x16x32_f16(wfrag[rt][kk], bf0, acc[rt][0], 0, 0, 0);
          acc[rt][1] = __builtin_amdgcn_mfma_f32_16x16x32_f16(wfrag[rt][kk], bf1, acc[rt][1], 0, 0, 0);
        }
      }
      #pragma unroll
      for (int rt = 0; rt < 4; ++rt)
        #pragma unroll
        for (int bt = 0; bt < 2; ++bt)
          #pragma unroll
          for (int p = 0; p < 4; ++p)
            part[wid][rt * 16 + hi * 4 + p][bt * 16 + lr] = acc[rt][bt][p];
    }
    __syncthreads();

    // ---- LSTM update: thread (ub, bb); h_t -> LDS tile ----
    {
      float g4[4];
      #pragma unroll
      for (int q = 0; q < 4; ++q) {
        int i = q * 16 + ub;
        float s = xg[q];
        #pragma unroll
        for (int w = 0; w < 8; ++w) s += part[w][i][bb];
        g4[q] = s;
      }
      float ig = 1.f / (1.f + __expf(-g4[0]));
      float fg = 1.f / (1.f + __expf(-g4[1]));
      float gg = tanhf(g4[2]);
      float og = 1.f / (1.f + __expf(-g4[3]));
      creg = fg * creg + ig * gg;
      float h = og * tanhf(creg);
      hs_out[bb][ub] = (f16)h;
    }
    __syncthreads();   // hs_out complete; part/hl free for next iteration

    // ---- wave 0: burst-store the 1KB chunk (64x16B), drain, post flag ----
    if (wid == 0) {
      const ull* src = (const ull*)&hs_out[0][0];
      ull d0 = src[lane * 2], d1 = src[lane * 2 + 1];
      ull* dst = (ull*)(HS2 + ((size_t)t * 64 + bid) * 512);
      __hip_atomic_store(dst + lane * 2,     d0, __ATOMIC_RELAXED, __HIP_MEMORY_SCOPE_AGENT);
      __hip_atomic_store(dst + lane * 2 + 1, d1, __ATOMIC_RELAXED, __HIP_MEMORY_SCOPE_AGENT);
      if (t != Tt - 1) {
        asm volatile("s_waitcnt vmcnt(0)" ::: "memory");  // chunk at coherence point
        if (lane == 0)
          __hip_atomic_store(&bar[bid], (unsigned)(t + 1),
                             __ATOMIC_RELAXED, __HIP_MEMORY_SCOPE_AGENT);
      }
    }
  }
}

extern "C" void kernel_launch(void* const* d_in, const int* in_sizes, int n_in,
                              void* d_out, int out_size, void* d_ws, size_t ws_size,
                              hipStream_t stream) {
  const float* z     = (const float*)d_in[0];
  const int*   x     = (const int*)d_in[1];
  const float* W_h   = (const float*)d_in[2];
  const float* b_h   = (const float*)d_in[3];
  const float* emb   = (const float*)d_in[4];
  const float* W_ih  = (const float*)d_in[5];
  const float* W_hh  = (const float*)d_in[6];
  const float* b_ih  = (const float*)d_in[7];
  const float* b_hh  = (const float*)d_in[8];
  const float* W_out = (const float*)d_in[9];
  const float* b_out = (const float*)d_in[10];
  float* out = (float*)d_out;

  char* ws = (char*)d_ws;
  size_t off = 0;
  auto carve = [&](size_t n) { char* p = ws + off; off += (n + 255) & ~(size_t)255; return p; };
  f16*   E16    = (f16*)carve((size_t)BT * DE * 2);     // 4 MB
  f16*   Wih16  = (f16*)carve((size_t)G4 * DE * 2);     // 4 MB
  f16*   Whh16  = (f16*)carve((size_t)G4 * HID * 2);    // 8 MB
  f16*   Wout16 = (f16*)carve((size_t)VOC * HID * 2);   // 64 MB
  float* XG2    = (float*)carve((size_t)BT * G4 * 4);   // 64 MB, [g][b][t]
  f16*   HS2    = (f16*)carve((size_t)BT * HID * 2);    // 8 MB, [t][blk][b][u]
  f16*   h0f    = (f16*)carve((size_t)Bb * HID * 2);
  float* bs     = (float*)carve((size_t)G4 * 4);
  unsigned* bar = (unsigned*)carve(256);

  (void)hipMemsetAsync(bar, 0, 256, stream);   // reset grid flags each call

  cvt_kernel<<<2048, 256, 0, stream>>>(W_ih,  Wih16,  G4 * DE / 4);
  cvt_kernel<<<2048, 256, 0, stream>>>(W_hh,  Whh16,  G4 * HID / 4);
  cvt_kernel<<<2048, 256, 0, stream>>>(W_out, Wout16, VOC * HID / 4);
  gather_kernel<<<BT * DE / 8 / 256, 256, 0, stream>>>(emb, x, E16);
  bsum_kernel<<<16, 256, 0, stream>>>(b_ih, b_hh, bs, G4);
  h0_kernel<<<128, 256, 0, stream>>>(z, W_h, b_h, h0f);

  dim3 g1(G4 / 128, BT / 128);     // 32 x 32
  gemm_kernel<true, false><<<g1, 256, 0, stream>>>(E16, Wih16, bs, XG2, BT, G4, DE);

  lstm_kernel<<<NB, 512, 0, stream>>>(Whh16, XG2, h0f, HS2, bar);

  dim3 g2(VOC / 128, BT / 128);    // 250 x 32
  gemm_kernel<false, true><<<g2, 256, 0, stream>>>(HS2, Wout16, b_out, out, BT, VOC, HID);
}

// Round 8
// 1185.258 us; speedup vs baseline: 1.4788x; 1.4788x over previous
//
#include <hip/hip_runtime.h>

typedef _Float16 f16;
typedef _Float16 f16x8 __attribute__((ext_vector_type(8)));
typedef _Float16 f16x4 __attribute__((ext_vector_type(4)));
typedef float    f32x4 __attribute__((ext_vector_type(4)));
typedef unsigned long long ull;

static constexpr int Bb  = 32;
static constexpr int Tt  = 128;
static constexpr int HID = 1024;
static constexpr int ZD  = 256;
static constexpr int DE  = 512;
static constexpr int VOC = 32000;
static constexpr int BT  = Bb * Tt;   // 4096
static constexpr int G4  = 4 * HID;   // 4096
static constexpr int NB  = 64;        // lstm blocks (16 hidden units each)
// HS2 slot layout: slot s in [0,128], chunk blk in [0,64), [b][u] inside:
//   half index = s*32768 + blk*512 + b*16 + u.  Slot s holds h_{s-1} (h0 in slot 0).

// ---- async global->LDS, 16B per lane; LDS dest = wave-uniform base + lane*16 ----
__device__ __forceinline__ void gld_lds16(const void* g, void* l) {
  __builtin_amdgcn_global_load_lds((const __attribute__((address_space(1))) unsigned int*)g,
                                   (__attribute__((address_space(3))) unsigned int*)l,
                                   16, 0, 0);
}

// ---------------- f32 -> f16 convert (vectorized) ----------------
__global__ void cvt_kernel(const float* __restrict__ s, f16* __restrict__ d, int n4) {
  int i = blockIdx.x * blockDim.x + threadIdx.x;
  int st = gridDim.x * blockDim.x;
  for (; i < n4; i += st) {
    float4 v = ((const float4*)s)[i];
    f16x4 o = { (f16)v.x, (f16)v.y, (f16)v.z, (f16)v.w };
    ((f16x4*)d)[i] = o;
  }
}

// ---------------- embedding gather -> f16 ----------------
__global__ void gather_kernel(const float* __restrict__ emb, const int* __restrict__ x,
                              f16* __restrict__ E) {
  int g = blockIdx.x * 256 + threadIdx.x;   // BT*DE/8 threads
  int m = g >> 6, seg = (g & 63) * 8;
  int idx = x[m];
  const float* src = emb + (size_t)idx * DE + seg;
  float4 a = *(const float4*)src;
  float4 b = *(const float4*)(src + 4);
  f16x8 o = { (f16)a.x,(f16)a.y,(f16)a.z,(f16)a.w,(f16)b.x,(f16)b.y,(f16)b.z,(f16)b.w };
  *(f16x8*)(E + (size_t)m * DE + seg) = o;
}

// ---------------- bias sum ----------------
__global__ void bsum_kernel(const float* __restrict__ a, const float* __restrict__ b,
                            float* __restrict__ o, int n) {
  int i = blockIdx.x * blockDim.x + threadIdx.x;
  if (i < n) o[i] = a[i] + b[i];
}

// ---------------- h0 = tanh(z @ W_h^T + b_h) -> HS2 slot 0 (chunk layout) --------
__global__ __launch_bounds__(256) void h0_kernel(const float* __restrict__ z,
                                                 const float* __restrict__ W_h,
                                                 const float* __restrict__ b_h,
                                                 f16* __restrict__ h0c) {
  __shared__ float zs[32][260];
  __shared__ float wsl[8][260];
  const int jc = blockIdx.x, tid = threadIdx.x;
  #pragma unroll
  for (int it = 0; it < 8; ++it) {
    int idx = it * 256 + tid;
    float4 v = ((const float4*)z)[idx];
    int b = idx >> 6, k = (idx & 63) * 4;
    zs[b][k] = v.x; zs[b][k+1] = v.y; zs[b][k+2] = v.z; zs[b][k+3] = v.w;
  }
  #pragma unroll
  for (int it = 0; it < 2; ++it) {
    int idx = it * 256 + tid;
    float4 v = ((const float4*)(W_h + (size_t)jc * 8 * ZD))[idx];
    int r = idx >> 6, k = (idx & 63) * 4;
    wsl[r][k] = v.x; wsl[r][k+1] = v.y; wsl[r][k+2] = v.z; wsl[r][k+3] = v.w;
  }
  __syncthreads();
  const int b = tid >> 3, jj = tid & 7;
  const int j = jc * 8 + jj;
  float acc = b_h[j];
  for (int k = 0; k < ZD; ++k) acc += zs[b][k] * wsl[jj][k];
  h0c[(size_t)(j >> 4) * 512 + b * 16 + (j & 15)] = (f16)tanhf(acc);
}

// ---------------- GEMM: C = A[M,K] @ B[N,K]^T + bias[N]  (f16 in, f32 out) --------
// XGOUT: C laid out [g][b][t] float (for the x-gate GEMM).
// AHS2 : A is the LSTM h-state in slot/chunk layout; A[m][k] (m=b*128+t, k=j) at
//        half-index ((m&127)+1)*32768 + (k>>4)*512 + (m>>7)*16 + (k&15).
template <bool XGOUT, bool AHS2>
__global__ __launch_bounds__(256, 2) void gemm_kernel(
    const f16* __restrict__ A, const f16* __restrict__ B,
    const float* __restrict__ bias, float* __restrict__ C,
    int M, int N, int K) {
  __shared__ f16 As[128 * 64];
  __shared__ f16 Bs[128 * 64];
  const int n0 = blockIdx.x * 128, m0 = blockIdx.y * 128;
  const int tid = threadIdx.x, wid = tid >> 6, lane = tid & 63;
  const int wm = wid >> 1, wn = wid & 1;
  const int sr = lane >> 3, sk = (lane & 7) * 8;
  f32x4 acc[4][4] = {};
  for (int k0 = 0; k0 < K; k0 += 64) {
    __syncthreads();
    #pragma unroll
    for (int i = 0; i < 4; ++i) {
      int rr = (wid * 4 + i) * 8;
      const f16* asrc;
      if (AHS2) {
        int m = m0 + rr + sr, k = k0 + sk;
        asrc = A + (size_t)((m & 127) + 1) * 32768 + (size_t)(k >> 4) * 512
                 + (m >> 7) * 16 + (k & 15);
      } else {
        asrc = A + (size_t)(m0 + rr + sr) * K + k0 + sk;
      }
      gld_lds16(asrc, &As[rr * 64]);
      gld_lds16(B + (size_t)(n0 + rr + sr) * K + k0 + sk, &Bs[rr * 64]);
    }
    __syncthreads();
    #pragma unroll
    for (int ks = 0; ks < 2; ++ks) {
      f16x8 af[4], bf[4];
      #pragma unroll
      for (int mt = 0; mt < 4; ++mt)
        af[mt] = *(const f16x8*)&As[(wm * 64 + mt * 16 + (lane & 15)) * 64 + ks * 32 + (lane >> 4) * 8];
      #pragma unroll
      for (int nt = 0; nt < 4; ++nt)
        bf[nt] = *(const f16x8*)&Bs[(wn * 64 + nt * 16 + (lane & 15)) * 64 + ks * 32 + (lane >> 4) * 8];
      #pragma unroll
      for (int mt = 0; mt < 4; ++mt)
        #pragma unroll
        for (int nt = 0; nt < 4; ++nt)
          acc[mt][nt] = __builtin_amdgcn_mfma_f32_16x16x32_f16(af[mt], bf[nt], acc[mt][nt], 0, 0, 0);
    }
  }
  #pragma unroll
  for (int nt = 0; nt < 4; ++nt) {
    int col = n0 + wn * 64 + nt * 16 + (lane & 15);
    float bv = bias[col];
    #pragma unroll
    for (int mt = 0; mt < 4; ++mt) {
      int row = m0 + wm * 64 + mt * 16 + (lane >> 4) * 4;
      if (XGOUT) {
        int b = row >> 7, t0 = row & 127;
        float4 v = { acc[mt][nt][0] + bv, acc[mt][nt][1] + bv,
                     acc[mt][nt][2] + bv, acc[mt][nt][3] + bv };
        *(float4*)&C[((size_t)col * 32 + b) * 128 + t0] = v;
      } else {
        #pragma unroll
        for (int p = 0; p < 4; ++p)
          C[(size_t)(row + p) * N + col] = acc[mt][nt][p] + bv;
      }
    }
  }
}

// ---------------- persistent LSTM recurrence (v7: v5 + packed exchange) ----------
// 64 blocks x 512 threads (8 waves). Block bid owns 16 hidden units (64 gate rows),
// W_hh fragments in VGPRs (wave wid owns k-range wid*128..+128).
// Exchange via HS2 slot/chunk layout: producer stores are per-thread 2B direct from
// registers but each wave's 64 stores form ONE contiguous 128B line of the block's
// 1KB chunk (agent-scope -> IF coherence point, no fences/wbl2/inv anywhere).
// Consumer: wave 0 polls the 64 flags (64 polling waves grid-wide), syncthreads
// releases, then all 8 waves stage 8 chunks each as contiguous 16B loads.
__global__ __launch_bounds__(512, 1) void lstm_kernel(
    const f16* __restrict__ Whh16,   // [4096][1024]
    const float* __restrict__ XG2,   // [g][b][t] : ((g*32)+b)*128+t
    f16* __restrict__ HS2,           // slot/chunk layout, slots 0..128
    unsigned int* __restrict__ bar) {// bar[0..63]: per-block ready-slot flags
  const int bid = blockIdx.x, tid = threadIdx.x;
  const int lane = tid & 63, wid = tid >> 6;
  const int lr = lane & 15, hi = lane >> 4;
  const int j0 = bid * 16;
  __shared__ __align__(16) f16 hl2[64][512];       // h_{t-1} chunks [blk][b*16+u]
  __shared__ float part[8][64][33];                // per-wave K-partials

  // preload W fragments (once): wave wid covers k in [wid*128, wid*128+128)
  f16x8 wfrag[4][4];
  #pragma unroll
  for (int rt = 0; rt < 4; ++rt) {                 // rt = gate q; unit row = lr
    int g = rt * HID + j0 + lr;
    #pragma unroll
    for (int kk = 0; kk < 4; ++kk)
      wfrag[rt][kk] = *(const f16x8*)(Whh16 + (size_t)g * HID + wid * 128 + kk * 32 + hi * 8);
  }

  const int ub = tid & 15, bb = tid >> 4;          // thread owns (unit ub, batch bb)
  float creg = 0.f;

  for (int t = 0; t < Tt; ++t) {
    // ---- XG prefetch (plain cached loads; 128B line serves 32 steps from L2) ----
    float xg[4];
    #pragma unroll
    for (int q = 0; q < 4; ++q)
      xg[q] = XG2[((size_t)(q * HID + j0 + ub) * 32 + bb) * 128 + t];

    // ---- wait for slot t: wave 0 polls all 64 flags, barrier releases the rest ----
    if (t > 0) {
      if (wid == 0) {
        const unsigned tgt = (unsigned)t;
        for (;;) {
          unsigned f = __hip_atomic_load(&bar[lane], __ATOMIC_RELAXED, __HIP_MEMORY_SCOPE_AGENT);
          if (__all(f >= tgt)) break;
        }
      }
      __syncthreads();
    }

    // ---- stage slot t: wave wid loads chunks 8*wid..+8 (16B contiguous/lane) ----
    {
      const f16* slot = HS2 + (size_t)t * 32768;
      ull tmp[8][2];
      #pragma unroll
      for (int c = 0; c < 8; ++c) {
        const ull* src = (const ull*)(slot + (wid * 8 + c) * 512);
        tmp[c][0] = __hip_atomic_load(src + lane * 2,     __ATOMIC_RELAXED, __HIP_MEMORY_SCOPE_AGENT);
        tmp[c][1] = __hip_atomic_load(src + lane * 2 + 1, __ATOMIC_RELAXED, __HIP_MEMORY_SCOPE_AGENT);
      }
      #pragma unroll
      for (int c = 0; c < 8; ++c) {
        int blk = wid * 8 + c;
        *(ull*)&hl2[blk][lane * 8]     = tmp[c][0];
        *(ull*)&hl2[blk][lane * 8 + 4] = tmp[c][1];
      }
    }
    __syncthreads();

    // ---- gate MFMA: C[64 gate rows][32 batches], this wave's k-eighth ----
    {
      f32x4 acc[4][2] = {};
      #pragma unroll
      for (int kk = 0; kk < 4; ++kk) {
        int ko = wid * 128 + kk * 32 + hi * 8;
        int c = ko >> 4, uo = ko & 15;
        f16x8 bf0 = *(const f16x8*)&hl2[c][lr * 16 + uo];
        f16x8 bf1 = *(const f16x8*)&hl2[c][(16 + lr) * 16 + uo];
        #pragma unroll
        for (int rt = 0; rt < 4; ++rt) {
          acc[rt][0] = __builtin_amdgcn_mfma_f32_16x16x32_f16(wfrag[rt][kk], bf0, acc[rt][0], 0, 0, 0);
          acc[rt][1] = __builtin_amdgcn_mfma_f32_16x16x32_f16(wfrag[rt][kk], bf1, acc[rt][1], 0, 0, 0);
        }
      }
      #pragma unroll
      for (int rt = 0; rt < 4; ++rt)
        #pragma unroll
        for (int bt = 0; bt < 2; ++bt)
          #pragma unroll
          for (int p = 0; p < 4; ++p)
            part[wid][rt * 16 + hi * 4 + p][bt * 16 + lr] = acc[rt][bt][p];
    }
    __syncthreads();

    // ---- LSTM update: thread (ub, bb); store h_t into slot t+1 (128B/wave) ----
    {
      float g4[4];
      #pragma unroll
      for (int q = 0; q < 4; ++q) {
        int i = q * 16 + ub;
        float s = xg[q];
        #pragma unroll
        for (int w = 0; w < 8; ++w) s += part[w][i][bb];
        g4[q] = s;
      }
      float ig = 1.f / (1.f + __expf(-g4[0]));
      float fg = 1.f / (1.f + __expf(-g4[1]));
      float gg = tanhf(g4[2]);
      float og = 1.f / (1.f + __expf(-g4[3]));
      creg = fg * creg + ig * gg;
      float h = og * tanhf(creg);
      union { f16 h; unsigned short u; } cv;
      cv.h = (f16)h;
      __hip_atomic_store((unsigned short*)(HS2 + (size_t)(t + 1) * 32768 + bid * 512 + tid),
                         cv.u, __ATOMIC_RELAXED, __HIP_MEMORY_SCOPE_AGENT);
    }

    // ---- post ready flag for slot t+1 ----
    if (t != Tt - 1) {
      asm volatile("s_waitcnt vmcnt(0)" ::: "memory");  // my chunk bytes are at IF
      __syncthreads();                                  // => whole chunk is
      if (tid == 0)
        __hip_atomic_store(&bar[bid], (unsigned)(t + 1),
                           __ATOMIC_RELAXED, __HIP_MEMORY_SCOPE_AGENT);
    }
  }
}

extern "C" void kernel_launch(void* const* d_in, const int* in_sizes, int n_in,
                              void* d_out, int out_size, void* d_ws, size_t ws_size,
                              hipStream_t stream) {
  const float* z     = (const float*)d_in[0];
  const int*   x     = (const int*)d_in[1];
  const float* W_h   = (const float*)d_in[2];
  const float* b_h   = (const float*)d_in[3];
  const float* emb   = (const float*)d_in[4];
  const float* W_ih  = (const float*)d_in[5];
  const float* W_hh  = (const float*)d_in[6];
  const float* b_ih  = (const float*)d_in[7];
  const float* b_hh  = (const float*)d_in[8];
  const float* W_out = (const float*)d_in[9];
  const float* b_out = (const float*)d_in[10];
  float* out = (float*)d_out;

  char* ws = (char*)d_ws;
  size_t off = 0;
  auto carve = [&](size_t n) { char* p = ws + off; off += (n + 255) & ~(size_t)255; return p; };
  f16*   E16    = (f16*)carve((size_t)BT * DE * 2);       // 4 MB
  f16*   Wih16  = (f16*)carve((size_t)G4 * DE * 2);       // 4 MB
  f16*   Whh16  = (f16*)carve((size_t)G4 * HID * 2);      // 8 MB
  f16*   Wout16 = (f16*)carve((size_t)VOC * HID * 2);     // 64 MB
  float* XG2    = (float*)carve((size_t)BT * G4 * 4);     // 64 MB, [g][b][t]
  f16*   HS2    = (f16*)carve((size_t)129 * 64 * 512 * 2);// 8.4 MB, slots 0..128
  float* bs     = (float*)carve((size_t)G4 * 4);
  unsigned* bar = (unsigned*)carve(256);

  (void)hipMemsetAsync(bar, 0, 256, stream);   // reset grid flags each call

  cvt_kernel<<<2048, 256, 0, stream>>>(W_ih,  Wih16,  G4 * DE / 4);
  cvt_kernel<<<2048, 256, 0, stream>>>(W_hh,  Whh16,  G4 * HID / 4);
  cvt_kernel<<<2048, 256, 0, stream>>>(W_out, Wout16, VOC * HID / 4);
  gather_kernel<<<BT * DE / 8 / 256, 256, 0, stream>>>(emb, x, E16);
  bsum_kernel<<<16, 256, 0, stream>>>(b_ih, b_hh, bs, G4);
  h0_kernel<<<128, 256, 0, stream>>>(z, W_h, b_h, HS2);   // writes slot 0

  dim3 g1(G4 / 128, BT / 128);     // 32 x 32
  gemm_kernel<true, false><<<g1, 256, 0, stream>>>(E16, Wih16, bs, XG2, BT, G4, DE);

  lstm_kernel<<<NB, 512, 0, stream>>>(Whh16, XG2, HS2, bar);

  dim3 g2(VOC / 128, BT / 128);    // 250 x 32
  gemm_kernel<false, true><<<g2, 256, 0, stream>>>(HS2, Wout16, b_out, out, BT, VOC, HID);
}